// Round 8
// baseline (181.670 us; speedup 1.0000x reference)
//
#include <hip/hip_runtime.h>

#define IMG_H 1080
#define IMG_W 1920
#define CH 3

__global__ __launch_bounds__(256, 8)
void dssim_l1_kernel(const float* __restrict__ pred,
                     const float* __restrict__ gt,
                     float* __restrict__ out) {
    constexpr float K1 = 81.0f * 0.0001f;        // 81*C1
    constexpr float K2 = 81.0f * 0.0009f;        // 81*C2
    constexpr float A3 = 0.85f / 3.0f;
    constexpr float B3 = 0.15f / 3.0f;

    const int lane = threadIdx.x;                        // 0..63
    const int r    = blockIdx.y * 4 + threadIdx.y;       // output row
    const int b    = blockIdx.z;
    const int c0   = blockIdx.x * 128 + 2 * lane;        // first of 2 output cols

    const int rm = (r == 0) ? 1 : r - 1;                 // reflect
    const int rp = (r == IMG_H - 1) ? IMG_H - 2 : r + 1;

    // halo column: lane 0 needs c0-1 (reflect at image edge -> 1),
    //              lane 63 needs c0+2 (reflect 1920 -> 1918)
    const int hcol = (lane == 0) ? ((c0 == 0) ? 1 : c0 - 1)
                                 : ((c0 + 2 >= IMG_W) ? IMG_W - 2 : c0 + 2);
    const bool is_edge = (lane == 0) || (lane == 63);

    const size_t img = (size_t)IMG_H * IMG_W;
    const float* __restrict__ bx = pred + (size_t)b * CH * img;
    const float* __restrict__ by = gt   + (size_t)b * CH * img;

    // vertical accumulators: per channel, per window position (c0-1,c0,c1,c1+1)
    float vx[CH][4], vy[CH][4], vxx[CH][4], vyy[CH][4], vxy[CH][4];

#define LOADROW(R, X2, Y2, HX, HY)                                          \
    {                                                                       \
        const unsigned ro_ = (unsigned)(R) * IMG_W;                         \
        _Pragma("unroll")                                                   \
        for (int c = 0; c < CH; ++c) {                                      \
            X2[c] = *reinterpret_cast<const float2*>(bx + (size_t)c * img + ro_ + c0); \
            Y2[c] = *reinterpret_cast<const float2*>(by + (size_t)c * img + ro_ + c0); \
        }                                                                   \
        if (is_edge) {                                                      \
            _Pragma("unroll")                                               \
            for (int c = 0; c < CH; ++c) {                                  \
                HX[c] = bx[(size_t)c * img + ro_ + hcol];                   \
                HY[c] = by[(size_t)c * img + ro_ + hcol];                   \
            }                                                               \
        }                                                                   \
    }

#define CONSUME(X2, Y2, HX, HY, FIRST)                                      \
    {                                                                       \
        _Pragma("unroll")                                                   \
        for (int c = 0; c < CH; ++c) {                                      \
            float xm = __shfl_up(X2[c].y, 1);                               \
            float xp = __shfl_down(X2[c].x, 1);                             \
            float ym = __shfl_up(Y2[c].y, 1);                               \
            float yp = __shfl_down(Y2[c].x, 1);                             \
            if (lane == 0)  { xm = HX[c]; ym = HY[c]; }                     \
            if (lane == 63) { xp = HX[c]; yp = HY[c]; }                     \
            const float wx[4] = { xm, X2[c].x, X2[c].y, xp };               \
            const float wy[4] = { ym, Y2[c].x, Y2[c].y, yp };               \
            _Pragma("unroll")                                               \
            for (int k = 0; k < 4; ++k) {                                   \
                if (FIRST) {                                                \
                    vx[c][k]  = wx[k];                                      \
                    vy[c][k]  = wy[k];                                      \
                    vxx[c][k] = wx[k] * wx[k];                              \
                    vyy[c][k] = wy[k] * wy[k];                              \
                    vxy[c][k] = wx[k] * wy[k];                              \
                } else {                                                    \
                    vx[c][k] += wx[k];                                      \
                    vy[c][k] += wy[k];                                      \
                    vxx[c][k] = fmaf(wx[k], wx[k], vxx[c][k]);              \
                    vyy[c][k] = fmaf(wy[k], wy[k], vyy[c][k]);              \
                    vxy[c][k] = fmaf(wx[k], wy[k], vxy[c][k]);              \
                }                                                           \
            }                                                               \
        }                                                                   \
    }

    float2 xA[CH], yA[CH], xB[CH], yB[CH];
    float hxA[CH], hyA[CH], hxB[CH], hyB[CH];

    LOADROW(rm, xA, yA, hxA, hyA);          // row r-1 in flight
    LOADROW(r,  xB, yB, hxB, hyB);          // row r   in flight
    CONSUME(xA, yA, hxA, hyA, true);        // waits only on first batch
    LOADROW(rp, xA, yA, hxA, hyA);          // row r+1 in flight (reuse bufs)

    // L1 term from row r center values
    float l10 = 0.f, l11 = 0.f;
#pragma unroll
    for (int c = 0; c < CH; ++c) {
        l10 += fabsf(xB[c].x - yB[c].x);
        l11 += fabsf(xB[c].y - yB[c].y);
    }

    CONSUME(xB, yB, hxB, hyB, false);       // row r
    CONSUME(xA, yA, hxA, hyA, false);       // row r+1

    // epilogue: horizontal 3-sums + SSIM per output column
    float res0 = B3 * l10;
    float res1 = B3 * l11;
#pragma unroll
    for (int c = 0; c < CH; ++c) {
        const float tx  = vx[c][1]  + vx[c][2];
        const float ty  = vy[c][1]  + vy[c][2];
        const float txx = vxx[c][1] + vxx[c][2];
        const float tyy = vyy[c][1] + vyy[c][2];
        const float txy = vxy[c][1] + vxy[c][2];
#pragma unroll
        for (int j = 0; j < 2; ++j) {
            const int e = (j == 0) ? 0 : 3;
            const float ax  = tx  + vx[c][e];
            const float ay  = ty  + vy[c][e];
            const float axx = txx + vxx[c][e];
            const float ayy = tyy + vyy[c][e];
            const float axy = txy + vxy[c][e];

            // SSIM scaled by 81 (cancels in n/d): see R3 derivation
            const float u = ax * ay;
            const float v = fmaf(ay, ay, ax * ax);
            const float w = axx + ayy;
            const float num1 = fmaf(2.0f, u, K1);
            const float num2 = fmaf(18.0f, axy, fmaf(-2.0f, u, K2));
            const float den1 = v + K1;
            const float den2 = fmaf(9.0f, w, K2) - v;
            float s = fmaf(-0.5f, (num1 * num2) * __builtin_amdgcn_rcpf(den1 * den2), 0.5f);
            s = fminf(fmaxf(s, 0.0f), 1.0f);
            if (j == 0) res0 = fmaf(A3, s, res0);
            else        res1 = fmaf(A3, s, res1);
        }
    }

    float2 o; o.x = res0; o.y = res1;
    *reinterpret_cast<float2*>(out + ((size_t)b * IMG_H + r) * IMG_W + c0) = o;

#undef CONSUME
#undef LOADROW
}

extern "C" void kernel_launch(void* const* d_in, const int* in_sizes, int n_in,
                              void* d_out, int out_size, void* d_ws, size_t ws_size,
                              hipStream_t stream) {
    const float* pred = (const float*)d_in[0];
    const float* gt   = (const float*)d_in[1];
    float* out = (float*)d_out;

    dim3 block(64, 4, 1);
    dim3 grid(IMG_W / 128, IMG_H / 4, 4);   // 15 x 270 x 4
    dssim_l1_kernel<<<grid, block, 0, stream>>>(pred, gt, out);
}

// Round 9
// 101.991 us; speedup vs baseline: 1.7812x; 1.7812x over previous
//
#include <hip/hip_runtime.h>

#define IMG_H 1080
#define IMG_W 1920
#define CH 3
#define GPW 480u   // 4-col groups per image row (1920/4)

__global__ __launch_bounds__(256)
void dssim_l1_kernel(const float* __restrict__ pred,
                     const float* __restrict__ gt,
                     float* __restrict__ out) {
    constexpr float K1 = 81.0f * 0.0001f;        // 81*C1
    constexpr float K2 = 81.0f * 0.0009f;        // 81*C2
    constexpr float A3 = 0.85f / 3.0f;
    constexpr float B3 = 0.15f / 3.0f;

    const int lane = threadIdx.x & 63;
    const unsigned flat = blockIdx.x * 256u + threadIdx.x;
    const unsigned g  = flat % GPW;              // col group 0..479
    const unsigned rr = flat / GPW;
    const unsigned r  = rr % IMG_H;              // output row
    const unsigned b  = rr / IMG_H;              // batch
    const int c0 = (int)g * 4;                   // first of 4 output cols

    const unsigned rm = (r == 0) ? 1u : r - 1u;                      // reflect rows
    const unsigned rp = (r == IMG_H - 1) ? (IMG_H - 2u) : r + 1u;

    // wave-edge halo column (lane 0 needs c0-1, lane 63 needs c0+4);
    // clamped — at image edges the value is overridden by in-register reflect
    const int hcol = (lane == 0) ? max(c0 - 1, 0) : min(c0 + 4, IMG_W - 1);
    const bool is_edge = (lane == 0) || (lane == 63);

    const size_t img = (size_t)IMG_H * IMG_W;
    const float* __restrict__ bx = pred + (size_t)b * CH * img;
    const float* __restrict__ by = gt   + (size_t)b * CH * img;

    // ---- issue ALL loads upfront: 18 aligned float4 + 18 predicated halo ----
    float4 xq[3][CH], yq[3][CH];
    float hx[3][CH], hy[3][CH];
    const unsigned ro[3] = { rm * IMG_W, r * IMG_W, rp * IMG_W };

#pragma unroll
    for (int i = 0; i < 3; ++i) {
#pragma unroll
        for (int c = 0; c < CH; ++c) {
            const size_t base = (size_t)c * img + ro[i];
            xq[i][c] = *reinterpret_cast<const float4*>(bx + base + c0);
            yq[i][c] = *reinterpret_cast<const float4*>(by + base + c0);
        }
    }
    if (is_edge) {
#pragma unroll
        for (int i = 0; i < 3; ++i) {
#pragma unroll
            for (int c = 0; c < CH; ++c) {
                const size_t base = (size_t)c * img + ro[i];
                hx[i][c] = bx[base + hcol];
                hy[i][c] = by[base + hcol];
            }
        }
    }

    // per (channel, output col): vertical sums of x, y, (xx+yy), xy
    float accx[CH][4], accy[CH][4], accw[CH][4], accxy[CH][4];

#define CONSUME(I, FIRST)                                                   \
    _Pragma("unroll")                                                       \
    for (int c = 0; c < CH; ++c) {                                          \
        const float4 qx = xq[I][c], qy = yq[I][c];                          \
        float xm = __shfl_up(qx.w, 1);                                      \
        float ym = __shfl_up(qy.w, 1);                                      \
        float xp = __shfl_down(qx.x, 1);                                    \
        float yp = __shfl_down(qy.x, 1);                                    \
        if (lane == 0)  { xm = hx[I][c]; ym = hy[I][c]; }                   \
        if (lane == 63) { xp = hx[I][c]; yp = hy[I][c]; }                   \
        if (g == 0u)       { xm = qx.y; ym = qy.y; }   /* refl(-1)=1 */     \
        if (g == GPW - 1u) { xp = qx.z; yp = qy.z; }   /* refl(1920)=1918 */\
        const float tx[6] = { xm, qx.x, qx.y, qx.z, qx.w, xp };             \
        const float ty[6] = { ym, qy.x, qy.y, qy.z, qy.w, yp };             \
        float pw[6], pxy[6];                                                \
        _Pragma("unroll")                                                   \
        for (int t = 0; t < 6; ++t) {                                       \
            pw[t]  = fmaf(tx[t], tx[t], ty[t] * ty[t]);                     \
            pxy[t] = tx[t] * ty[t];                                         \
        }                                                                   \
        _Pragma("unroll")                                                   \
        for (int j = 0; j < 4; ++j) {                                       \
            const float sx_ = tx[j] + tx[j + 1] + tx[j + 2];                \
            const float sy_ = ty[j] + ty[j + 1] + ty[j + 2];                \
            const float sw_ = pw[j] + pw[j + 1] + pw[j + 2];                \
            const float sp_ = pxy[j] + pxy[j + 1] + pxy[j + 2];             \
            if (FIRST) {                                                    \
                accx[c][j] = sx_;  accy[c][j] = sy_;                        \
                accw[c][j] = sw_;  accxy[c][j] = sp_;                       \
            } else {                                                        \
                accx[c][j] += sx_;  accy[c][j] += sy_;                      \
                accw[c][j] += sw_;  accxy[c][j] += sp_;                     \
            }                                                               \
        }                                                                   \
    }

    CONSUME(0, true)

    // L1 term from center row raw values
    float l1a[4] = { 0.f, 0.f, 0.f, 0.f };
#pragma unroll
    for (int c = 0; c < CH; ++c) {
        l1a[0] += fabsf(xq[1][c].x - yq[1][c].x);
        l1a[1] += fabsf(xq[1][c].y - yq[1][c].y);
        l1a[2] += fabsf(xq[1][c].z - yq[1][c].z);
        l1a[3] += fabsf(xq[1][c].w - yq[1][c].w);
    }

    CONSUME(1, false)
    CONSUME(2, false)
#undef CONSUME

    // ---- SSIM epilogue (moments scaled by 81; cancels in n/d) ----
    float rv[4];
#pragma unroll
    for (int j = 0; j < 4; ++j) {
        float acc = B3 * l1a[j];
#pragma unroll
        for (int c = 0; c < CH; ++c) {
            const float ax = accx[c][j], ay = accy[c][j];
            const float aw = accw[c][j], axy = accxy[c][j];
            const float u = ax * ay;
            const float v = fmaf(ay, ay, ax * ax);
            const float num1 = fmaf(2.0f, u, K1);
            const float num2 = fmaf(18.0f, axy, fmaf(-2.0f, u, K2));
            const float den1 = v + K1;
            const float den2 = fmaf(9.0f, aw, K2) - v;
            float s = fmaf(-0.5f, (num1 * num2) * __builtin_amdgcn_rcpf(den1 * den2), 0.5f);
            s = fminf(fmaxf(s, 0.0f), 1.0f);
            acc = fmaf(A3, s, acc);
        }
        rv[j] = acc;
    }

    float4 o; o.x = rv[0]; o.y = rv[1]; o.z = rv[2]; o.w = rv[3];
    *reinterpret_cast<float4*>(out + ((size_t)b * IMG_H + r) * IMG_W + c0) = o;
}

extern "C" void kernel_launch(void* const* d_in, const int* in_sizes, int n_in,
                              void* d_out, int out_size, void* d_ws, size_t ws_size,
                              hipStream_t stream) {
    const float* pred = (const float*)d_in[0];
    const float* gt   = (const float*)d_in[1];
    float* out = (float*)d_out;

    // 4 * 1080 * 480 threads = 2,073,600 -> 8100 blocks of 256
    dim3 block(256, 1, 1);
    dim3 grid(8100, 1, 1);
    dssim_l1_kernel<<<grid, block, 0, stream>>>(pred, gt, out);
}

// Round 10
// 62.722 us; speedup vs baseline: 2.8965x; 1.6261x over previous
//
#include <hip/hip_runtime.h>

#define IMG_H 1080
#define IMG_W 1920
#define CH 3

__global__ __launch_bounds__(256)
void dssim_l1_kernel(const float* __restrict__ pred,
                     const float* __restrict__ gt,
                     float* __restrict__ out) {
    constexpr float K1 = 81.0f * 0.0001f;        // 81*C1
    constexpr float K2 = 81.0f * 0.0009f;        // 81*C2
    constexpr float A3 = 0.85f / 3.0f;
    constexpr float B3 = 0.15f / 3.0f;

    const int lane = threadIdx.x;                               // 0..63
    const int r0   = (blockIdx.y * 4 + threadIdx.y) * 2;        // even output row
    const int b    = blockIdx.z;
    const int c0   = blockIdx.x * 128 + 2 * lane;               // 2 output cols

    // input rows r0-1 .. r0+2 with reflection
    const int rws[4] = { (r0 == 0) ? 1 : r0 - 1,
                         r0, r0 + 1,
                         (r0 + 2 == IMG_H) ? IMG_H - 2 : r0 + 2 };

    const bool l0 = (lane == 0), l63 = (lane == 63);
    const bool limg = l0  && (blockIdx.x == 0);    // image left edge lane
    const bool rimg = l63 && (blockIdx.x == 14);   // image right edge lane
    const int  hcol = l0 ? max(c0 - 1, 0) : min(c0 + 2, IMG_W - 1);
    const bool is_edge = l0 || l63;

    const size_t img = (size_t)IMG_H * IMG_W;
    const float* __restrict__ pb[2 * CH] = {
        pred + (size_t)b * CH * img,
        pred + (size_t)b * CH * img + img,
        pred + (size_t)b * CH * img + 2 * img,
        gt   + (size_t)b * CH * img,
        gt   + (size_t)b * CH * img + img,
        gt   + (size_t)b * CH * img + 2 * img };

    // ---- all 24 float2 loads (+ predicated halo) upfront ----
    float2 qx[4][CH], qy[4][CH];
    float hx[4][CH], hy[4][CH];
#pragma unroll
    for (int i = 0; i < 4; ++i) {
        const unsigned ro = (unsigned)rws[i] * IMG_W;
#pragma unroll
        for (int c = 0; c < CH; ++c) {
            qx[i][c] = *reinterpret_cast<const float2*>(pb[c]      + ro + c0);
            qy[i][c] = *reinterpret_cast<const float2*>(pb[CH + c] + ro + c0);
        }
        if (is_edge) {
#pragma unroll
            for (int c = 0; c < CH; ++c) {
                hx[i][c] = pb[c][ro + hcol];
                hy[i][c] = pb[CH + c][ro + hcol];
            }
        }
    }
    __builtin_amdgcn_sched_barrier(0);

    // window accumulators: [ch][col j] for stats x, y, w=xx+yy, p=xy
    float Ax[CH][2], Ay[CH][2], Aw[CH][2], Ap[CH][2];   // rows -1,0,1 -> out r0
    float Bx[CH][2], By[CH][2], Bw[CH][2], Bp[CH][2];   // rows 0,1,2  -> out r0+1

#define CONSUME(I, DOA, FIRSTA, DOB, FIRSTB)                                \
    _Pragma("unroll")                                                       \
    for (int c = 0; c < CH; ++c) {                                          \
        const float2 qx_ = qx[I][c], qy_ = qy[I][c];                        \
        float xm = __shfl_up(qx_.y, 1), ym = __shfl_up(qy_.y, 1);           \
        float xp = __shfl_down(qx_.x, 1), yp = __shfl_down(qy_.x, 1);       \
        if (l0)   { xm = hx[I][c]; ym = hy[I][c]; }                         \
        if (l63)  { xp = hx[I][c]; yp = hy[I][c]; }                         \
        if (limg) { xm = qx_.y; ym = qy_.y; }      /* reflect(-1)=1 */      \
        if (rimg) { xp = qx_.x; yp = qy_.x; }      /* reflect(1920)=1918 */ \
        const float tx[4] = { xm, qx_.x, qx_.y, xp };                       \
        const float ty[4] = { ym, qy_.x, qy_.y, yp };                       \
        float pw[4], pp[4];                                                 \
        _Pragma("unroll")                                                   \
        for (int t = 0; t < 4; ++t) {                                       \
            pw[t] = fmaf(tx[t], tx[t], ty[t] * ty[t]);                      \
            pp[t] = tx[t] * ty[t];                                          \
        }                                                                   \
        const float mx = tx[1] + tx[2], my = ty[1] + ty[2];                 \
        const float mw = pw[1] + pw[2], mp = pp[1] + pp[2];                 \
        const float wx0 = mx + tx[0], wx1 = mx + tx[3];                     \
        const float wy0 = my + ty[0], wy1 = my + ty[3];                     \
        const float ww0 = mw + pw[0], ww1 = mw + pw[3];                     \
        const float wp0 = mp + pp[0], wp1 = mp + pp[3];                     \
        if (DOA) {                                                          \
            if (FIRSTA) { Ax[c][0]=wx0; Ax[c][1]=wx1; Ay[c][0]=wy0;         \
                          Ay[c][1]=wy1; Aw[c][0]=ww0; Aw[c][1]=ww1;         \
                          Ap[c][0]=wp0; Ap[c][1]=wp1; }                     \
            else        { Ax[c][0]+=wx0; Ax[c][1]+=wx1; Ay[c][0]+=wy0;      \
                          Ay[c][1]+=wy1; Aw[c][0]+=ww0; Aw[c][1]+=ww1;      \
                          Ap[c][0]+=wp0; Ap[c][1]+=wp1; }                   \
        }                                                                   \
        if (DOB) {                                                          \
            if (FIRSTB) { Bx[c][0]=wx0; Bx[c][1]=wx1; By[c][0]=wy0;         \
                          By[c][1]=wy1; Bw[c][0]=ww0; Bw[c][1]=ww1;         \
                          Bp[c][0]=wp0; Bp[c][1]=wp1; }                     \
            else        { Bx[c][0]+=wx0; Bx[c][1]+=wx1; By[c][0]+=wy0;      \
                          By[c][1]+=wy1; Bw[c][0]+=ww0; Bw[c][1]+=ww1;      \
                          Bp[c][0]+=wp0; Bp[c][1]+=wp1; }                   \
        }                                                                   \
    }

    CONSUME(0, true, true,  false, false)   // row r0-1 -> A
    CONSUME(1, true, false, true,  true)    // row r0   -> A, B
    CONSUME(2, true, false, true,  false)   // row r0+1 -> A, B
    CONSUME(3, false, false, true, false)   // row r0+2 -> B
#undef CONSUME

    // L1 terms from raw center rows (index 1 -> out r0, index 2 -> out r0+1)
    float l1r0c0 = 0.f, l1r0c1 = 0.f, l1r1c0 = 0.f, l1r1c1 = 0.f;
#pragma unroll
    for (int c = 0; c < CH; ++c) {
        l1r0c0 += fabsf(qx[1][c].x - qy[1][c].x);
        l1r0c1 += fabsf(qx[1][c].y - qy[1][c].y);
        l1r1c0 += fabsf(qx[2][c].x - qy[2][c].x);
        l1r1c1 += fabsf(qx[2][c].y - qy[2][c].y);
    }

    // ---- SSIM epilogue (moments scaled by 81; cancels in n/d) ----
#define SSIM(AX, AY, AW, AP, ACC)                                           \
    {                                                                       \
        const float u = (AX) * (AY);                                        \
        const float v = fmaf((AY), (AY), (AX) * (AX));                      \
        const float num1 = fmaf(2.0f, u, K1);                               \
        const float num2 = fmaf(18.0f, (AP), fmaf(-2.0f, u, K2));           \
        const float den1 = v + K1;                                          \
        const float den2 = fmaf(9.0f, (AW), K2) - v;                        \
        float s = fmaf(-0.5f, (num1 * num2) *                               \
                       __builtin_amdgcn_rcpf(den1 * den2), 0.5f);           \
        s = fminf(fmaxf(s, 0.0f), 1.0f);                                    \
        ACC = fmaf(A3, s, ACC);                                             \
    }

    float o00 = B3 * l1r0c0, o01 = B3 * l1r0c1;
    float o10 = B3 * l1r1c0, o11 = B3 * l1r1c1;
#pragma unroll
    for (int c = 0; c < CH; ++c) {
        SSIM(Ax[c][0], Ay[c][0], Aw[c][0], Ap[c][0], o00)
        SSIM(Ax[c][1], Ay[c][1], Aw[c][1], Ap[c][1], o01)
        SSIM(Bx[c][0], By[c][0], Bw[c][0], Bp[c][0], o10)
        SSIM(Bx[c][1], By[c][1], Bw[c][1], Bp[c][1], o11)
    }
#undef SSIM

    float* op = out + ((size_t)b * IMG_H + r0) * IMG_W + c0;
    float2 v0; v0.x = o00; v0.y = o01;
    float2 v1; v1.x = o10; v1.y = o11;
    *reinterpret_cast<float2*>(op) = v0;
    *reinterpret_cast<float2*>(op + IMG_W) = v1;
}

extern "C" void kernel_launch(void* const* d_in, const int* in_sizes, int n_in,
                              void* d_out, int out_size, void* d_ws, size_t ws_size,
                              hipStream_t stream) {
    const float* pred = (const float*)d_in[0];
    const float* gt   = (const float*)d_in[1];
    float* out = (float*)d_out;

    dim3 block(64, 4, 1);
    dim3 grid(IMG_W / 128, IMG_H / 8, 4);   // 15 x 135 x 4
    dssim_l1_kernel<<<grid, block, 0, stream>>>(pred, gt, out);
}